// Round 4
// baseline (674.950 us; speedup 1.0000x reference)
//
#include <hip/hip_runtime.h>
#include <hip/hip_bf16.h>

typedef unsigned int u32;
typedef unsigned long long u64;

#define B 8
#define NANCH 100800
#define NCH 85
#define KPRE 1024
#define MAXDET 100
#define CONF 0.25f
#define IOU_T 0.45f
#define EPS_F 1e-7f
#define MAX_WH 7680.0f
#define CAP 4096
#define NBIN 257
#define BASEBITS 0x3E800000u  // bits of 0.25f

// ---------------- K1: score + argmax + fused per-batch histogram ----------------
// Wave per anchor. Argmax via max-reduce + equality ballot (ties -> lowest class
// index: classes 0..62 live in ballot m1 which wins over 63..79 in m2).
__global__ __launch_bounds__(256) void score_kernel(const float* __restrict__ pred,
                                                    u32* __restrict__ keys,
                                                    unsigned char* __restrict__ cls8,
                                                    u32* __restrict__ ghist) {
    __shared__ u32 lh[B * NBIN];
    for (int i = threadIdx.x; i < B * NBIN; i += 256) lh[i] = 0;
    __syncthreads();

    const int total = B * NANCH;
    int gtid = blockIdx.x * blockDim.x + threadIdx.x;
    int wid = gtid >> 6;
    int lane = threadIdx.x & 63;
    int nwaves = (gridDim.x * blockDim.x) >> 6;

    for (int a = wid; a < total; a += nwaves) {
        const float* p = pred + (size_t)a * NCH;
        float c1 = p[4 + lane];                       // col4 = obj, cols 5..67 = classes 0..62
        float c2 = (lane < 17) ? p[68 + lane] : 0.0f; // cols 68..84 = classes 63..79
        float obj = __shfl(c1, 0);
        float v1 = (lane >= 1) ? c1 * obj : -1.0f;
        float v2 = (lane < 17) ? c2 * obj : -1.0f;
        float v = fmaxf(v1, v2);
        #pragma unroll
        for (int m = 1; m < 64; m <<= 1) v = fmaxf(v, __shfl_xor(v, m));
        u64 m1 = __ballot(v1 == v);
        u64 m2 = __ballot(v2 == v);
        if (lane == 0) {
            int c = m1 ? (__builtin_ctzll(m1) - 1) : (63 + __builtin_ctzll(m2));
            bool valid = (obj > CONF) && (v > CONF);
            u32 k = valid ? __float_as_uint(v) : 0u;
            keys[a] = k;
            cls8[a] = (unsigned char)c;
            if (k) {
                int b = a / NANCH;
                u32 bin = (k - BASEBITS) >> 16;
                if (bin > 256) bin = 256;
                atomicAdd(&lh[b * NBIN + bin], 1u);
            }
        }
    }
    __syncthreads();
    for (int i = threadIdx.x; i < B * NBIN; i += 256) {
        u32 v = lh[i];
        if (v) atomicAdd(&ghist[i], v);  // no-return, fire-and-forget
    }
}

// ---------------- K2: per-batch mega-kernel: pivot -> filter -> sort -> boxes ->
//                     IOU mask -> greedy resolve -> output ----------------
__global__ __launch_bounds__(1024) void batch_kernel(const float* __restrict__ pred,
                                                     const u32* __restrict__ keys,
                                                     const unsigned char* __restrict__ cls8,
                                                     const u32* __restrict__ ghist,
                                                     u64* __restrict__ mask,
                                                     float* __restrict__ out) {
    #pragma clang fp contract(off)
    const int b = blockIdx.x;
    const int tid = threadIdx.x;

    __shared__ u64 items[CAP];       // 32 KB
    __shared__ float s_score[KPRE];  // 4 KB
    __shared__ float s_cls[KPRE];    // 4 KB
    __shared__ float4 s_box[KPRE];   // 16 KB
    __shared__ float4 s_obox[KPRE];  // 16 KB
    __shared__ float s_area[KPRE];   // 4 KB
    __shared__ u32 s_hist[NBIN];
    __shared__ int s_piv;
    __shared__ int s_cnt;
    __shared__ int s_keep[MAXDET];
    __shared__ int s_nk;

    // --- pivot (parallel load, serial scan of 257 LDS words) ---
    if (tid < NBIN) s_hist[tid] = ghist[b * NBIN + tid];
    if (tid == 0) s_cnt = 0;
    __syncthreads();
    if (tid == 0) {
        int cum = 0, piv = 0;
        for (int t = 256; t >= 0; --t) {
            cum += (int)s_hist[t];
            if (cum >= KPRE) { piv = t; break; }
        }
        s_piv = piv;
    }
    __syncthreads();
    const int piv = s_piv;

    // --- filter this batch's keys into LDS ---
    const u32* kb = keys + (size_t)b * NANCH;
    for (int i = tid; i < NANCH; i += 1024) {
        u32 k = kb[i];
        if (k) {
            u32 bin = (k - BASEBITS) >> 16;
            if (bin > 256) bin = 256;
            if ((int)bin >= piv) {
                int p = atomicAdd(&s_cnt, 1);
                if (p < CAP) items[p] = (((u64)(~k)) << 32) | (u32)i;
            }
        }
    }
    __syncthreads();
    int n = s_cnt; if (n > CAP) n = CAP;
    for (int i = tid; i < CAP; i += 1024)
        if (i >= n) items[i] = ~0ull;
    __syncthreads();

    // --- bitonic ascending sort of CAP u64 keys ---
    for (int k = 2; k <= CAP; k <<= 1) {
        for (int j = k >> 1; j >= 1; j >>= 1) {
            for (int p = tid; p < CAP / 2; p += 1024) {
                int i = ((p & ~(j - 1)) << 1) | (p & (j - 1));
                int pr = i | j;
                bool up = ((i & k) == 0);
                u64 a = items[i], c = items[pr];
                if ((a > c) == up) { items[i] = c; items[pr] = a; }
            }
            __syncthreads();
        }
    }

    // --- finalize slot tid: gather pred row, build boxes ---
    {
        u64 it = items[tid];
        u32 invk = (u32)(it >> 32);
        if (invk != 0xFFFFFFFFu && tid < n) {
            u32 k = ~invk;
            u32 idx = (u32)it;
            float score = __uint_as_float(k);
            const float* pb = pred + ((size_t)b * NANCH + idx) * NCH;
            float cx = pb[0], cy = pb[1], w = pb[2], h = pb[3];
            float x1 = cx - w * 0.5f;
            float y1 = cy - h * 0.5f;
            float x2 = cx + w * 0.5f;
            float y2 = cy + h * 0.5f;
            float clsf = (float)cls8[(size_t)b * NANCH + idx];
            float off = clsf * MAX_WH;
            float bx1 = x1 + off, by1 = y1 + off, bx2 = x2 + off, by2 = y2 + off;
            s_score[tid] = score;
            s_cls[tid] = clsf;
            s_box[tid] = make_float4(x1, y1, x2, y2);
            s_obox[tid] = make_float4(bx1, by1, bx2, by2);
            s_area[tid] = (bx2 - bx1) * (by2 - by1);
        } else {
            s_score[tid] = -1.0f;
            s_cls[tid] = 0.0f;
            s_box[tid] = make_float4(0.f, 0.f, 0.f, 0.f);
            s_obox[tid] = make_float4(0.f, 0.f, 0.f, 0.f);
            s_area[tid] = 0.0f;
        }
    }
    __syncthreads();

    // --- IOU bitmask: mask[r][w] for all w >= r/64 ---
    u64* mb = mask + (size_t)b * KPRE * 16;
    for (int w = 0; w < 16; ++w) {
        int nrows = (w + 1) * 64;
        for (int r = tid; r < nrows; r += 1024) {
            float4 rb = s_obox[r];
            float ra = s_area[r];
            u64 m = 0;
            #pragma unroll 4
            for (int j2 = 0; j2 < 64; ++j2) {
                int jg = w * 64 + j2;
                float4 cb = s_obox[jg];
                float ca = s_area[jg];
                float ltx = fmaxf(rb.x, cb.x);
                float lty = fmaxf(rb.y, cb.y);
                float rbx = fminf(rb.z, cb.z);
                float rby = fminf(rb.w, cb.w);
                float iw = fmaxf(rbx - ltx, 0.0f);
                float ih = fmaxf(rby - lty, 0.0f);
                float inter = iw * ih;
                float uni = ra + ca - inter;
                float iou = inter / (uni + EPS_F);
                if ((iou > IOU_T) && (jg > r)) m |= (1ull << j2);
            }
            mb[r * 16 + w] = m;
        }
    }
    __syncthreads();  // block-level visibility of mb writes

    // --- greedy sequential resolve on wave 0 ---
    if (tid < 64) {
        const int lane = tid;
        u64 rem = 0;  // lane w (<16) owns removed-bits for word w
        for (int w = 0; w < 16; ++w) {
            float s = s_score[w * 64 + lane];
            u64 bal = __ballot(s <= 0.0f);
            if (lane == w) rem = bal;
        }

        u64 mykept = 0;           // lane W holds keptbits of word W
        const int q = lane >> 4;  // quarter of rows this lane accumulates
        const int w16 = lane & 15;

        for (int W = 0; W < 16; ++W) {
            u64 cur = (u64)__shfl((long long)rem, W);
            u64 diag = mb[(W * 64 + lane) * 16 + W];
            u64 keptbits = 0;
            for (int t = 0; t < 64; ++t) {
                u64 dm = (u64)__shfl((long long)diag, t);
                if (!((cur >> t) & 1ull)) { keptbits |= (1ull << t); cur |= dm; }
            }
            if (lane == W) { rem = cur; mykept = keptbits; }

            u64 acc = 0;
            if (w16 > W) {
                #pragma unroll
                for (int t0 = 0; t0 < 16; ++t0) {
                    int t = q * 16 + t0;
                    u64 m = mb[(W * 64 + t) * 16 + w16];
                    acc |= ((keptbits >> t) & 1ull) ? m : 0ull;
                }
            }
            acc |= (u64)__shfl_xor((long long)acc, 16);
            acc |= (u64)__shfl_xor((long long)acc, 32);
            if (lane < 16 && lane > W) rem |= acc;
        }

        int nk = 0;
        for (int W = 0; W < 16; ++W) {
            u64 kb2 = (u64)__shfl((long long)mykept, W);
            if (lane == 0) {
                while (kb2 && nk < MAXDET) {
                    int t = __builtin_ctzll(kb2);
                    kb2 &= kb2 - 1;
                    s_keep[nk++] = W * 64 + t;
                }
            }
        }
        if (lane == 0) s_nk = nk;
    }
    __syncthreads();
    const int nk = s_nk;

    // --- output ---
    if (tid < MAXDET) {
        float o0 = 0, o1 = 0, o2 = 0, o3 = 0, o4 = 0, o5 = 0;
        if (tid < nk) {
            int i = s_keep[tid];
            float4 bx = s_box[i];
            o0 = bx.x; o1 = bx.y; o2 = bx.z; o3 = bx.w;
            o4 = s_score[i];
            o5 = s_cls[i];
        }
        float* po = out + ((size_t)b * MAXDET + tid) * 6;
        po[0] = o0; po[1] = o1; po[2] = o2; po[3] = o3; po[4] = o4; po[5] = o5;
    }
}

extern "C" void kernel_launch(void* const* d_in, const int* in_sizes, int n_in,
                              void* d_out, int out_size, void* d_ws, size_t ws_size,
                              hipStream_t stream) {
    const float* pred = (const float*)d_in[0];
    float* out = (float*)d_out;
    char* ws = (char*)d_ws;

    // workspace layout (bytes)
    u32* keys           = (u32*)(ws + 0);                 // 806400*4 = 3225600
    unsigned char* cls8 = (unsigned char*)(ws + 3225600); // 806400 -> 4032000
    u32* ghist          = (u32*)(ws + 4032000);           // 8*257*4 = 8224 -> 4040224
    u64* mask           = (u64*)(ws + 4040224);           // 8*1024*16*8 = 1048576 -> 5088800

    hipMemsetAsync(ghist, 0, B * NBIN * sizeof(u32), stream);
    score_kernel<<<2048, 256, 0, stream>>>(pred, keys, cls8, ghist);
    batch_kernel<<<B, 1024, 0, stream>>>(pred, keys, cls8, ghist, mask, out);
}

// Round 5
// 477.347 us; speedup vs baseline: 1.4140x; 1.4140x over previous
//
#include <hip/hip_runtime.h>
#include <hip/hip_bf16.h>

typedef unsigned int u32;
typedef unsigned long long u64;

#define B 8
#define NANCH 100800
#define NCH 85
#define KPRE 1024
#define MAXDET 100
#define CONF 0.25f
#define IOU_T 0.45f
#define EPS_F 1e-7f
#define MAX_WH 7680.0f
#define CAP 4096
#define NBIN 257
#define BASEBITS 0x3E800000u  // bits of 0.25f

// ---------------- K1: score + argmax + fused per-batch histogram ----------------
// Wave per anchor. Argmax via max-reduce + equality ballot (ties -> lowest class
// index: classes 0..62 live in ballot m1 which wins over 63..79 in m2).
__global__ __launch_bounds__(256) void score_kernel(const float* __restrict__ pred,
                                                    u32* __restrict__ keys,
                                                    unsigned char* __restrict__ cls8,
                                                    u32* __restrict__ ghist) {
    __shared__ u32 lh[B * NBIN];
    for (int i = threadIdx.x; i < B * NBIN; i += 256) lh[i] = 0;
    __syncthreads();

    const int total = B * NANCH;
    int gtid = blockIdx.x * blockDim.x + threadIdx.x;
    int wid = gtid >> 6;
    int lane = threadIdx.x & 63;
    int nwaves = (gridDim.x * blockDim.x) >> 6;

    for (int a = wid; a < total; a += nwaves) {
        const float* p = pred + (size_t)a * NCH;
        float c1 = p[4 + lane];                       // col4 = obj, cols 5..67 = classes 0..62
        float c2 = (lane < 17) ? p[68 + lane] : 0.0f; // cols 68..84 = classes 63..79
        float obj = __shfl(c1, 0);
        float v1 = (lane >= 1) ? c1 * obj : -1.0f;
        float v2 = (lane < 17) ? c2 * obj : -1.0f;
        float v = fmaxf(v1, v2);
        #pragma unroll
        for (int m = 1; m < 64; m <<= 1) v = fmaxf(v, __shfl_xor(v, m));
        u64 m1 = __ballot(v1 == v);
        u64 m2 = __ballot(v2 == v);
        if (lane == 0) {
            int c = m1 ? (__builtin_ctzll(m1) - 1) : (63 + __builtin_ctzll(m2));
            bool valid = (obj > CONF) && (v > CONF);
            u32 k = valid ? __float_as_uint(v) : 0u;
            keys[a] = k;
            cls8[a] = (unsigned char)c;
            if (k) {
                int b = a / NANCH;
                u32 bin = (k - BASEBITS) >> 16;
                if (bin > 256) bin = 256;
                atomicAdd(&lh[b * NBIN + bin], 1u);
            }
        }
    }
    __syncthreads();
    for (int i = threadIdx.x; i < B * NBIN; i += 256) {
        u32 v = lh[i];
        if (v) atomicAdd(&ghist[i], v);  // no-return, fire-and-forget
    }
}

// ---------------- K2: per-batch select: pivot -> filter -> sort -> boxes ->
//                     greedy register NMS -> output ----------------
__global__ __launch_bounds__(1024) void select_kernel(const float* __restrict__ pred,
                                                      const u32* __restrict__ keys,
                                                      const unsigned char* __restrict__ cls8,
                                                      const u32* __restrict__ ghist,
                                                      float* __restrict__ out) {
    #pragma clang fp contract(off)
    const int b = blockIdx.x;
    const int tid = threadIdx.x;

    __shared__ u64 items[CAP];       // 32 KB
    __shared__ float s_score[KPRE];  // 4 KB
    __shared__ float s_cls[KPRE];    // 4 KB
    __shared__ float4 s_box[KPRE];   // 16 KB
    __shared__ float4 s_obox[KPRE];  // 16 KB
    __shared__ float s_area[KPRE];   // 4 KB
    __shared__ u32 s_hist[NBIN];
    __shared__ int s_piv;
    __shared__ int s_cnt;
    __shared__ int s_keep[MAXDET];
    __shared__ int s_nk;

    // --- pivot ---
    if (tid < NBIN) s_hist[tid] = ghist[b * NBIN + tid];
    if (tid == 0) s_cnt = 0;
    __syncthreads();
    if (tid == 0) {
        int cum = 0, piv = 0;
        for (int t = 256; t >= 0; --t) {
            cum += (int)s_hist[t];
            if (cum >= KPRE) { piv = t; break; }
        }
        s_piv = piv;
    }
    __syncthreads();
    const int piv = s_piv;

    // --- filter this batch's keys into LDS (uint4-vectorized) ---
    const uint4* kb4 = (const uint4*)(keys + (size_t)b * NANCH);
    const int NV = NANCH / 4;  // 25200
    for (int j = tid; j < NV; j += 1024) {
        uint4 kv = kb4[j];
        u32 ks[4] = {kv.x, kv.y, kv.z, kv.w};
        #pragma unroll
        for (int e = 0; e < 4; ++e) {
            u32 k = ks[e];
            if (k) {
                u32 bin = (k - BASEBITS) >> 16;
                if (bin > 256) bin = 256;
                if ((int)bin >= piv) {
                    int p = atomicAdd(&s_cnt, 1);
                    if (p < CAP) items[p] = (((u64)(~k)) << 32) | (u32)(j * 4 + e);
                }
            }
        }
    }
    __syncthreads();
    int n = s_cnt; if (n > CAP) n = CAP;

    // dynamic sort size: next pow2 >= max(n, 1024)
    int m = KPRE;
    while (m < n) m <<= 1;
    for (int i = tid; i < m; i += 1024)
        if (i >= n) items[i] = ~0ull;
    __syncthreads();

    // --- bitonic ascending sort of m u64 keys ---
    for (int k = 2; k <= m; k <<= 1) {
        for (int j = k >> 1; j >= 1; j >>= 1) {
            for (int p = tid; p < m / 2; p += 1024) {
                int i = ((p & ~(j - 1)) << 1) | (p & (j - 1));
                int pr = i | j;
                bool up = ((i & k) == 0);
                u64 a = items[i], c = items[pr];
                if ((a > c) == up) { items[i] = c; items[pr] = a; }
            }
            __syncthreads();
        }
    }

    // --- finalize slot tid: gather pred row, build boxes ---
    if (tid < KPRE) {
        u64 it = items[tid];
        u32 invk = (u32)(it >> 32);
        if (invk != 0xFFFFFFFFu && tid < n) {
            u32 k = ~invk;
            u32 idx = (u32)it;
            float score = __uint_as_float(k);
            const float* pb = pred + ((size_t)b * NANCH + idx) * NCH;
            float cx = pb[0], cy = pb[1], w = pb[2], h = pb[3];
            float x1 = cx - w * 0.5f;
            float y1 = cy - h * 0.5f;
            float x2 = cx + w * 0.5f;
            float y2 = cy + h * 0.5f;
            float clsf = (float)cls8[(size_t)b * NANCH + idx];
            float off = clsf * MAX_WH;
            float bx1 = x1 + off, by1 = y1 + off, bx2 = x2 + off, by2 = y2 + off;
            s_score[tid] = score;
            s_cls[tid] = clsf;
            s_box[tid] = make_float4(x1, y1, x2, y2);
            s_obox[tid] = make_float4(bx1, by1, bx2, by2);
            s_area[tid] = (bx2 - bx1) * (by2 - by1);
        } else {
            s_score[tid] = -1.0f;
            s_cls[tid] = 0.0f;
            s_box[tid] = make_float4(0.f, 0.f, 0.f, 0.f);
            s_obox[tid] = make_float4(0.f, 0.f, 0.f, 0.f);
            s_area[tid] = 0.0f;
        }
    }
    __syncthreads();

    // --- greedy NMS on wave 0: kept boxes live in registers (2 slots/lane) ---
    // Equivalence to reference scan: candidate i is suppressed iff IOU(i, j) >
    // thres for some kept j < i (suppressed/invalid entries never suppress).
    // Output = first MAXDET kept in sorted order -> early exit at kept==MAXDET.
    if (tid < 64) {
        const int lane = tid;
        float4 kb0 = make_float4(0, 0, 0, 0), kb1 = kb0;
        float ka0 = 0.0f, ka1 = 0.0f;
        int kept = 0;

        float sc_n = s_score[0];
        float4 cb_n = s_obox[0];
        float ca_n = s_area[0];

        for (int i = 0; i < KPRE; ++i) {
            float sc = sc_n;
            float4 cb = cb_n;
            float ca = ca_n;
            if (i + 1 < KPRE) {           // prefetch next candidate
                sc_n = s_score[i + 1];
                cb_n = s_obox[i + 1];
                ca_n = s_area[i + 1];
            }
            if (sc <= 0.0f) break;        // sorted: rest invalid

            bool sup0 = false, sup1 = false;
            if (lane < kept) {
                float ltx = fmaxf(cb.x, kb0.x);
                float lty = fmaxf(cb.y, kb0.y);
                float rbx = fminf(cb.z, kb0.z);
                float rby = fminf(cb.w, kb0.w);
                float iw = fmaxf(rbx - ltx, 0.0f);
                float ih = fmaxf(rby - lty, 0.0f);
                float inter = iw * ih;
                float uni = ca + ka0 - inter;   // area_i + area_j - inter
                sup0 = (inter / (uni + EPS_F)) > IOU_T;
            }
            if (lane + 64 < kept) {
                float ltx = fmaxf(cb.x, kb1.x);
                float lty = fmaxf(cb.y, kb1.y);
                float rbx = fminf(cb.z, kb1.z);
                float rby = fminf(cb.w, kb1.w);
                float iw = fmaxf(rbx - ltx, 0.0f);
                float ih = fmaxf(rby - lty, 0.0f);
                float inter = iw * ih;
                float uni = ca + ka1 - inter;
                sup1 = (inter / (uni + EPS_F)) > IOU_T;
            }
            u64 bal = __ballot(sup0 || sup1);
            if (bal == 0) {
                if (lane == 0) s_keep[kept] = i;
                if (kept < 64) {
                    if (lane == kept) { kb0 = cb; ka0 = ca; }
                } else {
                    if (lane == kept - 64) { kb1 = cb; ka1 = ca; }
                }
                ++kept;
                if (kept >= MAXDET) break;
            }
        }
        if (lane == 0) s_nk = kept;
    }
    __syncthreads();
    const int nk = s_nk;

    // --- output ---
    if (tid < MAXDET) {
        float o0 = 0, o1 = 0, o2 = 0, o3 = 0, o4 = 0, o5 = 0;
        if (tid < nk) {
            int i = s_keep[tid];
            float4 bx = s_box[i];
            o0 = bx.x; o1 = bx.y; o2 = bx.z; o3 = bx.w;
            o4 = s_score[i];
            o5 = s_cls[i];
        }
        float* po = out + ((size_t)b * MAXDET + tid) * 6;
        po[0] = o0; po[1] = o1; po[2] = o2; po[3] = o3; po[4] = o4; po[5] = o5;
    }
}

extern "C" void kernel_launch(void* const* d_in, const int* in_sizes, int n_in,
                              void* d_out, int out_size, void* d_ws, size_t ws_size,
                              hipStream_t stream) {
    const float* pred = (const float*)d_in[0];
    float* out = (float*)d_out;
    char* ws = (char*)d_ws;

    // workspace layout (bytes)
    u32* keys           = (u32*)(ws + 0);                 // 806400*4 = 3225600
    unsigned char* cls8 = (unsigned char*)(ws + 3225600); // 806400 -> 4032000
    u32* ghist          = (u32*)(ws + 4032000);           // 8*257*4 = 8224 -> 4040224

    hipMemsetAsync(ghist, 0, B * NBIN * sizeof(u32), stream);
    score_kernel<<<2048, 256, 0, stream>>>(pred, keys, cls8, ghist);
    select_kernel<<<B, 1024, 0, stream>>>(pred, keys, cls8, ghist, out);
}